// Round 9
// baseline (79.514 us; speedup 1.0000x reference)
//
#include <hip/hip_runtime.h>
#include <hip/hip_bf16.h>

// out[k,s] = sum_{g: seq[g]==k} exp(A[gi,s] + 1 - pos[g]*B[gi,s]),
// N=1000, S=32, M=2M, K=100k.
//
// Round 9 (structure: bucket partition + fused sort/register-reduce, zero
// per-lane atomics). Changes vs r8:
//  - AB2p table preloaded into LDS (128 KiB): gather addr calc collapses to
//    v_and+v_add (payload's gi<<7 field IS the byte offset), latency 200->~60cy,
//    and reduce's L2 gather traffic goes to zero.
//  - accumulate unrolled 4x: 4 independent ds_read/exp chains.
//  - total reduce LDS = 145.5 KiB (1 block/CU, 16 waves — same occupancy as
//    measured r8; we cut issue count + latency instead).

#define CHUNK 8192        // genes per partition block
#define NBMAX 1024        // max buckets (K <= 131072)
#define CAPLG 12          // per-bucket region = 4096 entries
#define CAP   (1 << CAPLG)
#define SORTC 4096        // sorted-chunk capacity in fused reduce (u32)

__device__ inline float fast_exp2(float x) {
    float r;
    asm("v_exp_f32 %0, %1" : "=v"(r) : "v"(x));
    return r;
}

// ---- 0: pack AB2p[gi*32+lane] = f16((A+1)*log2e) | bf16(B*log2e/2^15)<<16
__global__ __launch_bounds__(256) void prep_kernel(
    const float* __restrict__ A, const float* __restrict__ B,
    unsigned* __restrict__ AB2p, int NS)
{
    const int i = blockIdx.x * 256 + threadIdx.x;
    if (i >= NS) return;
    const int gi = i >> 5, lane = i & 31;
    const float a2 = (A[i] + 1.0f) * 1.44269504f;
    const float b2 = B[i] * (1.44269504f / 32768.0f);
    const _Float16 ha = (_Float16)a2;                       // RNE cvt
    const unsigned short ua = __builtin_bit_cast(unsigned short, ha);
    unsigned bb = __float_as_uint(b2);
    bb = (bb + 0x7FFFu + ((bb >> 16) & 1u)) & 0xFFFF0000u;  // RNE to bf16
    AB2p[(gi << 5) + lane] = (unsigned)ua | bb;
}

// ---- 1: block-local counting sort by bucket + atomic range claim ----------
__global__ __launch_bounds__(1024) void partition_kernel(
    const float* __restrict__ pos, const int* __restrict__ gidx,
    const int* __restrict__ sidx, int* __restrict__ gcur,
    unsigned* __restrict__ payload, int M, int NB)
{
    __shared__ int h[NBMAX];
    __shared__ int pfx[NBMAX];
    __shared__ int cur[NBMAX];
    __shared__ int wsum[16];
    __shared__ unsigned stg_p[CHUNK];        // 32 KB packed payload
    __shared__ unsigned short stg_b[CHUNK];  // 16 KB bucket of each slot
    const int t = threadIdx.x, blk = blockIdx.x;
    const int i0 = blk * CHUNK;
    const int n = min(CHUNK, M - i0);

    h[t] = 0;
    __syncthreads();
    for (int j = t; j < n; j += 1024) atomicAdd(&h[sidx[i0 + j] >> 7], 1);
    __syncthreads();

    // block-wide exclusive scan over 1024 entries (wave shfl + wave sums)
    int incl;
    {
        const int v = h[t];
        incl = v;
#pragma unroll
        for (int d = 1; d < 64; d <<= 1) {
            const int x = __shfl_up(incl, d);
            if ((t & 63) >= d) incl += x;
        }
        if ((t & 63) == 63) wsum[t >> 6] = incl;
        __syncthreads();
        if (t < 16) {
            const int wv = wsum[t];
            int winc = wv;
#pragma unroll
            for (int d = 1; d < 16; d <<= 1) {
                const int x = __shfl_up(winc, d, 16);
                if (t >= d) winc += x;
            }
            wsum[t] = winc - wv;
        }
        __syncthreads();
        const int ex = wsum[t >> 6] + incl - h[t];
        pfx[t] = ex;
        cur[t] = ex;
    }
    __syncthreads();

    // placement into LDS staging (sorted by bucket), pack payload u32:
    // local_seq(7) | gidx(10) | pos_q15(15)
    for (int j = t; j < n; j += 1024) {
        const int sx = sidx[i0 + j];
        const int b = sx >> 7;
        const float p = pos[i0 + j];
        int q = (int)fmaf(p, 32768.0f, 0.5f);
        q = min(q, 32767);
        const unsigned pl = (unsigned)(sx & 127)
                          | ((unsigned)gidx[i0 + j] << 7)
                          | ((unsigned)q << 17);
        const int d = atomicAdd(&cur[b], 1);
        stg_p[d] = pl;
        stg_b[d] = (unsigned short)b;
    }
    __syncthreads();

    // claim this block's range in each bucket's fixed region
    if (t < NB) {
        const int hc = h[t];
        int dst = t << CAPLG;
        if (hc > 0) dst += atomicAdd(&gcur[t], hc);
        cur[t] = dst;
    }
    __syncthreads();

    // coalesced flush; guard against (statistically impossible) overflow
    for (int tt = t; tt < n; tt += 1024) {
        const int b = stg_b[tt];
        const int r = cur[b] + (tt - pfx[b]);
        if ((r >> CAPLG) == b) payload[r] = stg_p[tt];
    }
}

// ---- 2: fused per-bucket sort-by-seq + register-accumulate reduce ---------
// LDS: AB2 table 128 KiB + sorted 16 KiB + tables 1.5 KiB = 145.5 KiB.
#define GENE(w, dst)                                                       \
    {                                                                      \
        const float qf = (float)((w) >> 17);                               \
        const unsigned ab = AB2lds[(((w) >> 2) & 0x7FE0u) + lane];         \
        float a2;                                                          \
        asm("v_cvt_f32_f16 %0, %1" : "=v"(a2) : "v"(ab));                  \
        dst += fast_exp2(fmaf(-qf, __int_as_float(ab & 0xFFFF0000u), a2)); \
    }

__global__ __launch_bounds__(1024, 4) void fused_reduce_kernel(
    const unsigned* __restrict__ AB2p, const unsigned* __restrict__ payload,
    const int* __restrict__ gcur, float* __restrict__ out, int K, int NS)
{
    __shared__ unsigned AB2lds[NBMAX * 32];  // 128 KiB genome table
    __shared__ unsigned sorted[SORTC];       // 16 KiB
    __shared__ int h[128];
    __shared__ int pfx[128];
    __shared__ int cur[128];
    const int t = threadIdx.x, bkt = blockIdx.x;
    const int lane = t & 31, grp = t >> 5;
    const int start = bkt << CAPLG;
    const int n_total = min(gcur[bkt], CAP);

    // preload genome table (coalesced, L2-resident source)
    for (int j = t; j < NS; j += 1024) AB2lds[j] = AB2p[j];

    float acc[4] = {0.0f, 0.0f, 0.0f, 0.0f};

    for (int c = start; c < start + n_total; c += SORTC) {
        const int n = min(SORTC, start + n_total - c);

        if (t < 128) h[t] = 0;
        __syncthreads();   // covers preload on first iteration too

        unsigned r0, r1, r2, r3;
        const bool v0 = t < n, v1 = t + 1024 < n, v2 = t + 2048 < n, v3 = t + 3072 < n;
        if (v0) { r0 = payload[c + t];        atomicAdd(&h[r0 & 127], 1); }
        if (v1) { r1 = payload[c + t + 1024]; atomicAdd(&h[r1 & 127], 1); }
        if (v2) { r2 = payload[c + t + 2048]; atomicAdd(&h[r2 & 127], 1); }
        if (v3) { r3 = payload[c + t + 3072]; atomicAdd(&h[r3 & 127], 1); }
        __syncthreads();

        // 128-entry exclusive scan by wave 0 (shfl, no barriers inside)
        if (t < 64) {
            const int e0 = h[2 * t], e1 = h[2 * t + 1];
            const int ps = e0 + e1;
            int incl = ps;
#pragma unroll
            for (int d = 1; d < 64; d <<= 1) {
                const int x = __shfl_up(incl, d);
                if (t >= d) incl += x;
            }
            const int ex = incl - ps;
            pfx[2 * t] = ex;          cur[2 * t] = ex;
            pfx[2 * t + 1] = ex + e0; cur[2 * t + 1] = ex + e0;
        }
        __syncthreads();

        if (v0) sorted[atomicAdd(&cur[r0 & 127], 1)] = r0;
        if (v1) sorted[atomicAdd(&cur[r1 & 127], 1)] = r1;
        if (v2) sorted[atomicAdd(&cur[r2 & 127], 1)] = r2;
        if (v3) sorted[atomicAdd(&cur[r3 & 127], 1)] = r3;
        __syncthreads();

        // register-accumulate: group owns local seqs 4*grp..4*grp+3;
        // unroll-4 = 4 independent ds_read/exp chains
#pragma unroll
        for (int q = 0; q < 4; q++) {
            const int ls = (grp << 2) | q;
            int i = pfx[ls];
            const int e = i + h[ls];
            float a0 = 0.0f, a1 = 0.0f, a2s = 0.0f, a3 = 0.0f;
            for (; i + 3 < e; i += 4) {
                const unsigned w0 = sorted[i];
                const unsigned w1 = sorted[i + 1];
                const unsigned w2 = sorted[i + 2];
                const unsigned w3 = sorted[i + 3];
                GENE(w0, a0); GENE(w1, a1); GENE(w2, a2s); GENE(w3, a3);
            }
            for (; i < e; i++) {
                const unsigned w0 = sorted[i];
                GENE(w0, a0);
            }
            acc[q] += (a0 + a1) + (a2s + a3);
        }
        __syncthreads();
    }

    const int seq0 = bkt << 7;
#pragma unroll
    for (int q = 0; q < 4; q++) {
        const int seq = seq0 + (grp << 2) + q;
        if (seq < K) out[(seq << 5) + lane] = acc[q];
    }
}

// ---- fallback (round-1 atomic version) ------------------------------------
__global__ __launch_bounds__(256) void scatter_exp_fallback(
    const float* __restrict__ A, const float* __restrict__ B,
    const float* __restrict__ pos, const int* __restrict__ gidx,
    const int* __restrict__ sidx, float* __restrict__ out, int M)
{
    const int lane = threadIdx.x & 31;
    int group = (int)((blockIdx.x * blockDim.x + threadIdx.x) >> 5);
    const int stride = (int)((gridDim.x * blockDim.x) >> 5);
    for (int g = group; g < M; g += stride) {
        const int gi = gidx[g];
        const int si = sidx[g];
        const float p = pos[g];
        const float a = A[(gi << 5) + lane];
        const float b = B[(gi << 5) + lane];
        atomicAdd(&out[(si << 5) + lane], __expf(fmaf(-p, b, a + 1.0f)));
    }
}

extern "C" void kernel_launch(void* const* d_in, const int* in_sizes, int n_in,
                              void* d_out, int out_size, void* d_ws, size_t ws_size,
                              hipStream_t stream)
{
    const float* A    = (const float*)d_in[0];   // [N,32]
    const float* B    = (const float*)d_in[1];   // [N,32]
    const float* pos  = (const float*)d_in[2];   // [M]
    const int*   gidx = (const int*)d_in[3];     // [M]
    const int*   sidx = (const int*)d_in[4];     // [M]
    float*       out  = (float*)d_out;           // [K,32]

    const int M  = in_sizes[2];
    const int NS = in_sizes[0];                  // N*32
    const int N  = NS / 32;
    const int K  = out_size / 32;
    const int NB = (K + 127) >> 7;               // 782 for K=100k
    const int NBLK = (M + CHUNK - 1) / CHUNK;    // 245 for M=2M

    // ws layout: gcur i32[NBMAX] | AB2p u32[N*32] | payload u32[NB<<CAPLG]
    char* ws = (char*)d_ws;
    size_t off = 0;
    int* gcur = (int*)(ws + off);       off += (size_t)NBMAX * sizeof(int);
    off = (off + 255) & ~(size_t)255;
    unsigned* AB2p = (unsigned*)(ws + off); off += (size_t)N * 32 * sizeof(unsigned);
    off = (off + 255) & ~(size_t)255;
    unsigned* payload = (unsigned*)(ws + off);
    const size_t need = off + ((size_t)NB << CAPLG) * sizeof(unsigned);

    // pack limits: local seq 7b, gidx 10b (N<=1024), pos_q 15b; mean bucket
    // fill M/NB must be well under CAP (guarded writes handle the tail)
    const bool packable = (NB <= NBMAX) && (K <= NBMAX * 128) && (N <= 1024)
                       && (M / (NB > 0 ? NB : 1) <= CAP / 4 * 3);
    if (!packable || ws_size < need) {
        hipMemsetAsync(d_out, 0, (size_t)out_size * sizeof(float), stream);
        scatter_exp_fallback<<<8192, 256, 0, stream>>>(A, B, pos, gidx, sidx, out, M);
        return;
    }

    hipMemsetAsync(gcur, 0, (size_t)NBMAX * sizeof(int), stream);
    prep_kernel     <<<(NS + 255) / 256, 256, 0, stream>>>(A, B, AB2p, NS);
    partition_kernel<<<NBLK, 1024, 0, stream>>>(pos, gidx, sidx, gcur, payload, M, NB);
    fused_reduce_kernel<<<NB, 1024, 0, stream>>>(AB2p, payload, gcur, out, K, NS);
}

// Round 10
// 70.842 us; speedup vs baseline: 1.1224x; 1.1224x over previous
//
#include <hip/hip_runtime.h>
#include <hip/hip_bf16.h>

// out[k,s] = sum_{g: seq[g]==k} exp(A[gi,s] + 1 - pos[g]*B[gi,s]),
// N=1000, S=32, M=2M, K=100k.
//
// Round 10 (structure: bucket partition + fused sort/register-reduce, zero
// per-lane atomics). Evidence through r9: 1024-thread blocks cap at ~51%
// occupancy (1 WG/CU) on this chip; LDS-resident table lost to that (r9).
// Changes vs r8:
//  - reduce: 512 threads, 64-seq buckets (NB=1563, CAP=2048, single chunk),
//    ~8.5 KB LDS -> 4 blocks/CU (32 waves); table gathered from L2 as in r8.
//  - rank-in-register sort: hist atomicAdd returns rank, scatter is plain
//    ds_write (LDS atomics 4M -> 2M).
//  - partition: 512 threads, CHUNK 4096, 48 KB LDS -> 3 blocks/CU.
//  - gcur zeroing folded into prep_kernel (one fewer dispatch).

#define CHUNK 4096        // genes per partition block
#define NBMAX 2048        // max buckets (K <= 131072 at 64 seq/bucket)
#define CAPLG 11          // per-bucket region = 2048 entries
#define CAP   (1 << CAPLG)

__device__ inline float fast_exp2(float x) {
    float r;
    asm("v_exp_f32 %0, %1" : "=v"(r) : "v"(x));
    return r;
}

// ---- 0: pack AB2p[gi*32+lane] = f16((A+1)*log2e) | bf16(B*log2e/2^15)<<16
//         and zero gcur[NBMAX]
__global__ __launch_bounds__(256) void prep_kernel(
    const float* __restrict__ A, const float* __restrict__ B,
    unsigned* __restrict__ AB2p, int* __restrict__ gcur, int NS)
{
    const int i = blockIdx.x * 256 + threadIdx.x;
    if (i < NBMAX) gcur[i] = 0;
    if (i >= NS) return;
    const float a2 = (A[i] + 1.0f) * 1.44269504f;
    const float b2 = B[i] * (1.44269504f / 32768.0f);
    const _Float16 ha = (_Float16)a2;                       // RNE cvt
    const unsigned short ua = __builtin_bit_cast(unsigned short, ha);
    unsigned bb = __float_as_uint(b2);
    bb = (bb + 0x7FFFu + ((bb >> 16) & 1u)) & 0xFFFF0000u;  // RNE to bf16
    AB2p[i] = (unsigned)ua | bb;
}

// ---- 1: block-local counting sort by 64-seq bucket + atomic range claim ---
__global__ __launch_bounds__(512) void partition_kernel(
    const float* __restrict__ pos, const int* __restrict__ gidx,
    const int* __restrict__ sidx, int* __restrict__ gcur,
    unsigned* __restrict__ payload, int M, int NB)
{
    __shared__ int h[NBMAX];                 // 8 KB
    __shared__ int pfx[NBMAX];               // 8 KB
    __shared__ int cur[NBMAX];               // 8 KB
    __shared__ int wsum[8];
    __shared__ unsigned stg_p[CHUNK];        // 16 KB packed payload
    __shared__ unsigned short stg_b[CHUNK];  // 8 KB bucket of each slot
    const int t = threadIdx.x, blk = blockIdx.x;
    const int i0 = blk * CHUNK;
    const int n = min(CHUNK, M - i0);

    for (int j = t; j < NBMAX; j += 512) h[j] = 0;
    __syncthreads();
    for (int j = t; j < n; j += 512) atomicAdd(&h[sidx[i0 + j] >> 6], 1);
    __syncthreads();

    // block-wide exclusive scan over 2048 bins: 4 bins/thread + wave scans
    {
        int v[4], s = 0;
#pragma unroll
        for (int j = 0; j < 4; j++) { v[j] = h[t * 4 + j]; s += v[j]; }
        int incl = s;
#pragma unroll
        for (int d = 1; d < 64; d <<= 1) {
            const int x = __shfl_up(incl, d);
            if ((t & 63) >= d) incl += x;
        }
        if ((t & 63) == 63) wsum[t >> 6] = incl;
        __syncthreads();
        if (t < 8) {
            const int wv = wsum[t];
            int winc = wv;
#pragma unroll
            for (int d = 1; d < 8; d <<= 1) {
                const int x = __shfl_up(winc, d, 8);
                if (t >= d) winc += x;
            }
            wsum[t] = winc - wv;
        }
        __syncthreads();
        int ex = wsum[t >> 6] + incl - s;
#pragma unroll
        for (int j = 0; j < 4; j++) {
            pfx[t * 4 + j] = ex;
            cur[t * 4 + j] = ex;
            ex += v[j];
        }
    }
    __syncthreads();

    // placement into LDS staging (sorted by bucket), pack payload u32:
    // local_seq(6) | gidx(10) | unused(1) | pos_q15(15)
    for (int j = t; j < n; j += 512) {
        const int sx = sidx[i0 + j];
        const int b = sx >> 6;
        const float p = pos[i0 + j];
        int q = (int)fmaf(p, 32768.0f, 0.5f);
        q = min(q, 32767);
        const unsigned pl = (unsigned)(sx & 63)
                          | ((unsigned)gidx[i0 + j] << 6)
                          | ((unsigned)q << 17);
        const int d = atomicAdd(&cur[b], 1);
        stg_p[d] = pl;
        stg_b[d] = (unsigned short)b;
    }
    __syncthreads();

    // claim this block's range in each bucket's fixed region
    for (int b = t; b < NB; b += 512) {
        const int hc = h[b];
        int dst = b << CAPLG;
        if (hc > 0) dst += atomicAdd(&gcur[b], hc);
        cur[b] = dst;
    }
    __syncthreads();

    // coalesced flush; guard against (statistically impossible) overflow
    for (int tt = t; tt < n; tt += 512) {
        const int b = stg_b[tt];
        const int r = cur[b] + (tt - pfx[b]);
        if ((r >> CAPLG) == b) payload[r] = stg_p[tt];
    }
}

// ---- 2: fused per-bucket sort-by-seq + register-accumulate reduce ---------
// 512 threads = 16 groups of 32 lanes; group owns local seqs 4g..4g+3.
#define GENE(w, dst)                                                       \
    {                                                                      \
        const float qf = (float)((w) >> 17);                               \
        const unsigned ab = AB2p[(((w) >> 1) & 0x7FE0u) + lane];           \
        float a2;                                                          \
        asm("v_cvt_f32_f16 %0, %1" : "=v"(a2) : "v"(ab));                  \
        dst += fast_exp2(fmaf(-qf, __int_as_float(ab & 0xFFFF0000u), a2)); \
    }

__global__ __launch_bounds__(512) void fused_reduce_kernel(
    const unsigned* __restrict__ AB2p, const unsigned* __restrict__ payload,
    const int* __restrict__ gcur, float* __restrict__ out, int K)
{
    __shared__ unsigned sorted[CAP];   // 8 KB
    __shared__ int h[64];
    __shared__ int pfx[64];
    const int t = threadIdx.x, bkt = blockIdx.x;
    const int lane = t & 31, grp = t >> 5;
    const int start = bkt << CAPLG;
    const int n = min(gcur[bkt], CAP);

    if (t < 64) h[t] = 0;
    __syncthreads();

    // load whole region (4/thread); rank-in-register from hist atomicAdd
    unsigned r[4];
    int rk[4];
#pragma unroll
    for (int u = 0; u < 4; u++) {
        const int idx = t + u * 512;
        if (idx < n) {
            r[u] = payload[start + idx];
            rk[u] = atomicAdd(&h[r[u] & 63], 1);
        } else rk[u] = -1;
    }
    __syncthreads();

    // 64-bin exclusive scan by wave 0
    if (t < 64) {
        const int v = h[t];
        int incl = v;
#pragma unroll
        for (int d = 1; d < 64; d <<= 1) {
            const int x = __shfl_up(incl, d);
            if (t >= d) incl += x;
        }
        pfx[t] = incl - v;
    }
    __syncthreads();

    // scatter: plain ds_write (no atomics)
#pragma unroll
    for (int u = 0; u < 4; u++)
        if (rk[u] >= 0) sorted[pfx[r[u] & 63] + rk[u]] = r[u];
    __syncthreads();

    // register-accumulate; unroll-4 = 4 independent gather/exp chains
    float acc[4] = {0.0f, 0.0f, 0.0f, 0.0f};
#pragma unroll
    for (int q = 0; q < 4; q++) {
        const int ls = (grp << 2) | q;
        int i = pfx[ls];
        const int e = i + h[ls];
        float a0 = 0.0f, a1 = 0.0f, a2s = 0.0f, a3 = 0.0f;
        for (; i + 3 < e; i += 4) {
            const unsigned w0 = sorted[i];
            const unsigned w1 = sorted[i + 1];
            const unsigned w2 = sorted[i + 2];
            const unsigned w3 = sorted[i + 3];
            GENE(w0, a0); GENE(w1, a1); GENE(w2, a2s); GENE(w3, a3);
        }
        for (; i < e; i++) {
            const unsigned w0 = sorted[i];
            GENE(w0, a0);
        }
        acc[q] = (a0 + a1) + (a2s + a3);
    }

    const int seq0 = bkt << 6;
#pragma unroll
    for (int q = 0; q < 4; q++) {
        const int seq = seq0 + (grp << 2) + q;
        if (seq < K) out[(seq << 5) + lane] = acc[q];
    }
}

// ---- fallback (round-1 atomic version) ------------------------------------
__global__ __launch_bounds__(256) void scatter_exp_fallback(
    const float* __restrict__ A, const float* __restrict__ B,
    const float* __restrict__ pos, const int* __restrict__ gidx,
    const int* __restrict__ sidx, float* __restrict__ out, int M)
{
    const int lane = threadIdx.x & 31;
    int group = (int)((blockIdx.x * blockDim.x + threadIdx.x) >> 5);
    const int stride = (int)((gridDim.x * blockDim.x) >> 5);
    for (int g = group; g < M; g += stride) {
        const int gi = gidx[g];
        const int si = sidx[g];
        const float p = pos[g];
        const float a = A[(gi << 5) + lane];
        const float b = B[(gi << 5) + lane];
        atomicAdd(&out[(si << 5) + lane], __expf(fmaf(-p, b, a + 1.0f)));
    }
}

extern "C" void kernel_launch(void* const* d_in, const int* in_sizes, int n_in,
                              void* d_out, int out_size, void* d_ws, size_t ws_size,
                              hipStream_t stream)
{
    const float* A    = (const float*)d_in[0];   // [N,32]
    const float* B    = (const float*)d_in[1];   // [N,32]
    const float* pos  = (const float*)d_in[2];   // [M]
    const int*   gidx = (const int*)d_in[3];     // [M]
    const int*   sidx = (const int*)d_in[4];     // [M]
    float*       out  = (float*)d_out;           // [K,32]

    const int M  = in_sizes[2];
    const int NS = in_sizes[0];                  // N*32
    const int N  = NS / 32;
    const int K  = out_size / 32;
    const int NB = (K + 63) >> 6;                // 1563 for K=100k
    const int NBLK = (M + CHUNK - 1) / CHUNK;    // 489 for M=2M

    // ws layout: gcur i32[NBMAX] | AB2p u32[N*32] | payload u32[NB<<CAPLG]
    char* ws = (char*)d_ws;
    size_t off = 0;
    int* gcur = (int*)(ws + off);       off += (size_t)NBMAX * sizeof(int);
    off = (off + 255) & ~(size_t)255;
    unsigned* AB2p = (unsigned*)(ws + off); off += (size_t)N * 32 * sizeof(unsigned);
    off = (off + 255) & ~(size_t)255;
    unsigned* payload = (unsigned*)(ws + off);
    const size_t need = off + ((size_t)NB << CAPLG) * sizeof(unsigned);

    // pack limits: local seq 6b, gidx 10b (N<=1024), pos_q 15b; mean bucket
    // fill must be well under CAP (guarded writes handle the tail)
    const bool packable = (NB <= NBMAX) && (K <= NBMAX * 64) && (N <= 1024)
                       && (M / (NB > 0 ? NB : 1) <= CAP / 4 * 3);
    if (!packable || ws_size < need) {
        hipMemsetAsync(d_out, 0, (size_t)out_size * sizeof(float), stream);
        scatter_exp_fallback<<<8192, 256, 0, stream>>>(A, B, pos, gidx, sidx, out, M);
        return;
    }

    const int prep_grid = (max(NS, NBMAX) + 255) / 256;
    prep_kernel     <<<prep_grid, 256, 0, stream>>>(A, B, AB2p, gcur, NS);
    partition_kernel<<<NBLK, 512, 0, stream>>>(pos, gidx, sidx, gcur, payload, M, NB);
    fused_reduce_kernel<<<NB, 512, 0, stream>>>(AB2p, payload, gcur, out, K);
}

// Round 11
// 65.988 us; speedup vs baseline: 1.2050x; 1.0736x over previous
//
#include <hip/hip_runtime.h>
#include <hip/hip_bf16.h>

// out[k,s] = sum_{g: seq[g]==k} exp(A[gi,s] + 1 - pos[g]*B[gi,s]),
// N=1000, S=32, M=2M, K=100k.
//
// Round 11. Evidence: r8 partition config (1024t, CHUNK 8192, 128-seq
// buckets) is the cheap partition (~20us; 64-seq r10 doubled flush txns);
// r10 reduce config (512t => 4 blocks/CU) is the high-occupancy reduce.
// Combine both + wave-paired accumulation (two 32-lane halves of a wave
// process the SAME seq, consecutive genes -> wave-uniform control flow,
// half the iterations, final shfl_xor(32) merge).

#define CHUNK 8192        // genes per partition block
#define NBMAX 1024        // max buckets (K <= 131072 at 128 seq/bucket)
#define CAPLG 12          // per-bucket region = 4096 entries
#define CAP   (1 << CAPLG)

__device__ inline float fast_exp2(float x) {
    float r;
    asm("v_exp_f32 %0, %1" : "=v"(r) : "v"(x));
    return r;
}

// ---- 0: pack AB2p[gi*32+s] = f16((A+1)*log2e) | bf16(B*log2e/2^15)<<16
//         and zero gcur[NBMAX]
__global__ __launch_bounds__(256) void prep_kernel(
    const float* __restrict__ A, const float* __restrict__ B,
    unsigned* __restrict__ AB2p, int* __restrict__ gcur, int NS)
{
    const int i = blockIdx.x * 256 + threadIdx.x;
    if (i < NBMAX) gcur[i] = 0;
    if (i >= NS) return;
    const float a2 = (A[i] + 1.0f) * 1.44269504f;
    const float b2 = B[i] * (1.44269504f / 32768.0f);
    const _Float16 ha = (_Float16)a2;                       // RNE cvt
    const unsigned short ua = __builtin_bit_cast(unsigned short, ha);
    unsigned bb = __float_as_uint(b2);
    bb = (bb + 0x7FFFu + ((bb >> 16) & 1u)) & 0xFFFF0000u;  // RNE to bf16
    AB2p[i] = (unsigned)ua | bb;
}

// ---- 1: block-local counting sort by 128-seq bucket + atomic range claim --
// (r8 configuration: 1024 threads, CHUNK 8192)
__global__ __launch_bounds__(1024) void partition_kernel(
    const float* __restrict__ pos, const int* __restrict__ gidx,
    const int* __restrict__ sidx, int* __restrict__ gcur,
    unsigned* __restrict__ payload, int M, int NB)
{
    __shared__ int h[NBMAX];
    __shared__ int pfx[NBMAX];
    __shared__ int cur[NBMAX];
    __shared__ int wsum[16];
    __shared__ unsigned stg_p[CHUNK];        // 32 KB packed payload
    __shared__ unsigned short stg_b[CHUNK];  // 16 KB bucket of each slot
    const int t = threadIdx.x, blk = blockIdx.x;
    const int i0 = blk * CHUNK;
    const int n = min(CHUNK, M - i0);

    h[t] = 0;
    __syncthreads();
    for (int j = t; j < n; j += 1024) atomicAdd(&h[sidx[i0 + j] >> 7], 1);
    __syncthreads();

    // block-wide exclusive scan over 1024 bins (wave shfl + wave sums)
    {
        const int v = h[t];
        int incl = v;
#pragma unroll
        for (int d = 1; d < 64; d <<= 1) {
            const int x = __shfl_up(incl, d);
            if ((t & 63) >= d) incl += x;
        }
        if ((t & 63) == 63) wsum[t >> 6] = incl;
        __syncthreads();
        if (t < 16) {
            const int wv = wsum[t];
            int winc = wv;
#pragma unroll
            for (int d = 1; d < 16; d <<= 1) {
                const int x = __shfl_up(winc, d, 16);
                if (t >= d) winc += x;
            }
            wsum[t] = winc - wv;
        }
        __syncthreads();
        const int ex = wsum[t >> 6] + incl - v;
        pfx[t] = ex;
        cur[t] = ex;
    }
    __syncthreads();

    // placement into LDS staging (sorted by bucket), pack payload u32:
    // local_seq(7) | gidx(10) | pos_q15(15)
    for (int j = t; j < n; j += 1024) {
        const int sx = sidx[i0 + j];
        const int b = sx >> 7;
        const float p = pos[i0 + j];
        int q = (int)fmaf(p, 32768.0f, 0.5f);
        q = min(q, 32767);
        const unsigned pl = (unsigned)(sx & 127)
                          | ((unsigned)gidx[i0 + j] << 7)
                          | ((unsigned)q << 17);
        const int d = atomicAdd(&cur[b], 1);
        stg_p[d] = pl;
        stg_b[d] = (unsigned short)b;
    }
    __syncthreads();

    // claim this block's range in each bucket's fixed region
    if (t < NB) {
        const int hc = h[t];
        int dst = t << CAPLG;
        if (hc > 0) dst += atomicAdd(&gcur[t], hc);
        cur[t] = dst;
    }
    __syncthreads();

    // coalesced flush; guard against (statistically impossible) overflow
    for (int tt = t; tt < n; tt += 1024) {
        const int b = stg_b[tt];
        const int r = cur[b] + (tt - pfx[b]);
        if ((r >> CAPLG) == b) payload[r] = stg_p[tt];
    }
}

// ---- 2: fused per-bucket sort-by-seq + wave-paired register reduce --------
// 512 threads = 8 waves. Rank-in-register sort (8 entries/thread), then
// wave w owns local seqs 16w..16w+15; the two 32-lane halves process the
// same seq, consecutive genes (wave-uniform control flow).
#define GENE(w, dst)                                                        \
    {                                                                       \
        const float qf = (float)((w) >> 17);                                \
        const unsigned ab = AB2p[(((w) >> 2) & 0x7FE0u) + s32];             \
        float a2v;                                                          \
        asm("v_cvt_f32_f16 %0, %1" : "=v"(a2v) : "v"(ab));                  \
        dst += fast_exp2(fmaf(-qf, __int_as_float(ab & 0xFFFF0000u), a2v)); \
    }

__global__ __launch_bounds__(512) void fused_reduce_kernel(
    const unsigned* __restrict__ AB2p, const unsigned* __restrict__ payload,
    const int* __restrict__ gcur, float* __restrict__ out, int K)
{
    __shared__ unsigned sorted[CAP];   // 16 KB
    __shared__ int h[128];
    __shared__ int pfx[128];
    const int t = threadIdx.x, bkt = blockIdx.x;
    const int s32 = t & 31;            // sample
    const int half = (t >> 5) & 1;     // which gene of the pair
    const int wv = t >> 6;             // wave id 0..7
    const int start = bkt << CAPLG;
    const int n = min(gcur[bkt], CAP);

    if (t < 128) h[t] = 0;
    __syncthreads();

    // load whole region (8/thread); rank-in-register from hist atomicAdd
    unsigned r[8];
    int rk[8];
#pragma unroll
    for (int u = 0; u < 8; u++) {
        const int idx = t + u * 512;
        if (idx < n) {
            r[u] = payload[start + idx];
            rk[u] = atomicAdd(&h[r[u] & 127], 1);
        } else rk[u] = -1;
    }
    __syncthreads();

    // 128-bin exclusive scan by wave 0 (2 bins/lane)
    if (t < 64) {
        const int e0 = h[2 * t], e1 = h[2 * t + 1];
        const int ps = e0 + e1;
        int incl = ps;
#pragma unroll
        for (int d = 1; d < 64; d <<= 1) {
            const int x = __shfl_up(incl, d);
            if (t >= d) incl += x;
        }
        const int ex = incl - ps;
        pfx[2 * t] = ex;
        pfx[2 * t + 1] = ex + e0;
    }
    __syncthreads();

    // scatter: plain ds_write (no atomics)
#pragma unroll
    for (int u = 0; u < 8; u++)
        if (rk[u] >= 0) sorted[pfx[r[u] & 127] + rk[u]] = r[u];
    __syncthreads();

    // wave-paired accumulate: per seq, lanes 0-31 take gene i, 32-63 gene i+1
    const int seqbase = (bkt << 7) + (wv << 4);
    for (int q = 0; q < 16; q++) {
        const int ls = (wv << 4) + q;
        int i = pfx[ls];
        const int e = i + h[ls];
        float a0 = 0.0f, a1 = 0.0f;
        for (; i + 3 < e; i += 4) {           // 4 genes in flight per wave
            const unsigned w0 = sorted[i + half];
            const unsigned w1 = sorted[i + 2 + half];
            GENE(w0, a0); GENE(w1, a1);
        }
        for (; i + 1 < e; i += 2) {
            const unsigned w0 = sorted[i + half];
            GENE(w0, a0);
        }
        if (i < e && half == 0) {             // odd tail: lower half only
            const unsigned w0 = sorted[i];
            GENE(w0, a0);
        }
        float acc = a0 + a1;
        acc += __shfl_xor(acc, 32);           // merge the two halves
        const int seq = seqbase + q;
        if (half == 0 && seq < K) out[(seq << 5) + s32] = acc;
    }
}

// ---- fallback (round-1 atomic version) ------------------------------------
__global__ __launch_bounds__(256) void scatter_exp_fallback(
    const float* __restrict__ A, const float* __restrict__ B,
    const float* __restrict__ pos, const int* __restrict__ gidx,
    const int* __restrict__ sidx, float* __restrict__ out, int M)
{
    const int lane = threadIdx.x & 31;
    int group = (int)((blockIdx.x * blockDim.x + threadIdx.x) >> 5);
    const int stride = (int)((gridDim.x * blockDim.x) >> 5);
    for (int g = group; g < M; g += stride) {
        const int gi = gidx[g];
        const int si = sidx[g];
        const float p = pos[g];
        const float a = A[(gi << 5) + lane];
        const float b = B[(gi << 5) + lane];
        atomicAdd(&out[(si << 5) + lane], __expf(fmaf(-p, b, a + 1.0f)));
    }
}

extern "C" void kernel_launch(void* const* d_in, const int* in_sizes, int n_in,
                              void* d_out, int out_size, void* d_ws, size_t ws_size,
                              hipStream_t stream)
{
    const float* A    = (const float*)d_in[0];   // [N,32]
    const float* B    = (const float*)d_in[1];   // [N,32]
    const float* pos  = (const float*)d_in[2];   // [M]
    const int*   gidx = (const int*)d_in[3];     // [M]
    const int*   sidx = (const int*)d_in[4];     // [M]
    float*       out  = (float*)d_out;           // [K,32]

    const int M  = in_sizes[2];
    const int NS = in_sizes[0];                  // N*32
    const int N  = NS / 32;
    const int K  = out_size / 32;
    const int NB = (K + 127) >> 7;               // 782 for K=100k
    const int NBLK = (M + CHUNK - 1) / CHUNK;    // 245 for M=2M

    // ws layout: gcur i32[NBMAX] | AB2p u32[N*32] | payload u32[NB<<CAPLG]
    char* ws = (char*)d_ws;
    size_t off = 0;
    int* gcur = (int*)(ws + off);       off += (size_t)NBMAX * sizeof(int);
    off = (off + 255) & ~(size_t)255;
    unsigned* AB2p = (unsigned*)(ws + off); off += (size_t)N * 32 * sizeof(unsigned);
    off = (off + 255) & ~(size_t)255;
    unsigned* payload = (unsigned*)(ws + off);
    const size_t need = off + ((size_t)NB << CAPLG) * sizeof(unsigned);

    // pack limits: local seq 7b, gidx 10b (N<=1024), pos_q 15b; mean bucket
    // fill must be well under CAP (guarded writes handle the tail)
    const bool packable = (NB <= NBMAX) && (K <= NBMAX * 128) && (N <= 1024)
                       && (M / (NB > 0 ? NB : 1) <= CAP / 4 * 3);
    if (!packable || ws_size < need) {
        hipMemsetAsync(d_out, 0, (size_t)out_size * sizeof(float), stream);
        scatter_exp_fallback<<<8192, 256, 0, stream>>>(A, B, pos, gidx, sidx, out, M);
        return;
    }

    const int prep_grid = (max(NS, NBMAX) + 255) / 256;
    prep_kernel     <<<prep_grid, 256, 0, stream>>>(A, B, AB2p, gcur, NS);
    partition_kernel<<<NBLK, 1024, 0, stream>>>(pos, gidx, sidx, gcur, payload, M, NB);
    fused_reduce_kernel<<<NB, 512, 0, stream>>>(AB2p, payload, gcur, out, K);
}

// Round 12
// 60.100 us; speedup vs baseline: 1.3230x; 1.0980x over previous
//
#include <hip/hip_runtime.h>
#include <hip/hip_bf16.h>

// out[k,s] = sum_{g: seq[g]==k} exp(A[gi,s] + 1 - pos[g]*B[gi,s]),
// N=1000, S=32, M=2M, K=100k.
//
// Round 12. Reduce was invariant ~45us across r7-r11: issue-count x occupancy
// bound (occ 36%, ~13 insts/2 genes incl 64-bit addressing). Fixes:
//  - grid NB*2: each 512t block processes a 64-seq HALF of a 128-seq region
//    (filter on 1 bit) -> 4 blocks/CU, 32-wave theoretical occupancy.
//  - GENE addressing: payload bits [16:7] ARE the row byte offset ->
//    voff = (w & 0x1FF80) | (s32<<2) is one v_and_or_b32; saddr global load.
//  - paired LDS reads: lower half takes sorted[i,i+1], upper [i+2,i+3].
// Partition/prep unchanged (r8 config, measured cheap).

#define CHUNK 8192        // genes per partition block
#define NBMAX 1024        // max 128-seq buckets (K <= 131072)
#define CAPLG 12          // per-bucket region = 4096 entries
#define CAP   (1 << CAPLG)
#define SCAP  3072        // sorted capacity per half-region (mean 1280)

__device__ inline float fast_exp2(float x) {
    float r;
    asm("v_exp_f32 %0, %1" : "=v"(r) : "v"(x));
    return r;
}

// ---- 0: pack AB2p[gi*32+s] = f16((A+1)*log2e) | bf16(B*log2e/2^15)<<16
//         and zero gcur[NBMAX]
__global__ __launch_bounds__(256) void prep_kernel(
    const float* __restrict__ A, const float* __restrict__ B,
    unsigned* __restrict__ AB2p, int* __restrict__ gcur, int NS)
{
    const int i = blockIdx.x * 256 + threadIdx.x;
    if (i < NBMAX) gcur[i] = 0;
    if (i >= NS) return;
    const float a2 = (A[i] + 1.0f) * 1.44269504f;
    const float b2 = B[i] * (1.44269504f / 32768.0f);
    const _Float16 ha = (_Float16)a2;                       // RNE cvt
    const unsigned short ua = __builtin_bit_cast(unsigned short, ha);
    unsigned bb = __float_as_uint(b2);
    bb = (bb + 0x7FFFu + ((bb >> 16) & 1u)) & 0xFFFF0000u;  // RNE to bf16
    AB2p[i] = (unsigned)ua | bb;
}

// ---- 1: block-local counting sort by 128-seq bucket + atomic range claim --
__global__ __launch_bounds__(1024) void partition_kernel(
    const float* __restrict__ pos, const int* __restrict__ gidx,
    const int* __restrict__ sidx, int* __restrict__ gcur,
    unsigned* __restrict__ payload, int M, int NB)
{
    __shared__ int h[NBMAX];
    __shared__ int pfx[NBMAX];
    __shared__ int cur[NBMAX];
    __shared__ int wsum[16];
    __shared__ unsigned stg_p[CHUNK];        // 32 KB packed payload
    __shared__ unsigned short stg_b[CHUNK];  // 16 KB bucket of each slot
    const int t = threadIdx.x, blk = blockIdx.x;
    const int i0 = blk * CHUNK;
    const int n = min(CHUNK, M - i0);

    h[t] = 0;
    __syncthreads();
    for (int j = t; j < n; j += 1024) atomicAdd(&h[sidx[i0 + j] >> 7], 1);
    __syncthreads();

    // block-wide exclusive scan over 1024 bins (wave shfl + wave sums)
    {
        const int v = h[t];
        int incl = v;
#pragma unroll
        for (int d = 1; d < 64; d <<= 1) {
            const int x = __shfl_up(incl, d);
            if ((t & 63) >= d) incl += x;
        }
        if ((t & 63) == 63) wsum[t >> 6] = incl;
        __syncthreads();
        if (t < 16) {
            const int wv = wsum[t];
            int winc = wv;
#pragma unroll
            for (int d = 1; d < 16; d <<= 1) {
                const int x = __shfl_up(winc, d, 16);
                if (t >= d) winc += x;
            }
            wsum[t] = winc - wv;
        }
        __syncthreads();
        const int ex = wsum[t >> 6] + incl - v;
        pfx[t] = ex;
        cur[t] = ex;
    }
    __syncthreads();

    // placement into LDS staging (sorted by bucket), pack payload u32:
    // local_seq(7) | gidx(10) | pos_q15(15)
    for (int j = t; j < n; j += 1024) {
        const int sx = sidx[i0 + j];
        const int b = sx >> 7;
        const float p = pos[i0 + j];
        int q = (int)fmaf(p, 32768.0f, 0.5f);
        q = min(q, 32767);
        const unsigned pl = (unsigned)(sx & 127)
                          | ((unsigned)gidx[i0 + j] << 7)
                          | ((unsigned)q << 17);
        const int d = atomicAdd(&cur[b], 1);
        stg_p[d] = pl;
        stg_b[d] = (unsigned short)b;
    }
    __syncthreads();

    // claim this block's range in each bucket's fixed region
    if (t < NB) {
        const int hc = h[t];
        int dst = t << CAPLG;
        if (hc > 0) dst += atomicAdd(&gcur[t], hc);
        cur[t] = dst;
    }
    __syncthreads();

    // coalesced flush; guard against (statistically impossible) overflow
    for (int tt = t; tt < n; tt += 1024) {
        const int b = stg_b[tt];
        const int r = cur[b] + (tt - pfx[b]);
        if ((r >> CAPLG) == b) payload[r] = stg_p[tt];
    }
}

// ---- 2: fused half-region sort-by-seq + wave-paired register reduce -------
// Block = 512 threads = 8 waves; handles 64 seqs (half of a 128-seq region).
// Wave w owns local seqs 8w..8w+7; halves process consecutive genes.
#define GENE(w, dst)                                                        \
    {                                                                       \
        const float qf = (float)((w) >> 17);                                \
        const unsigned voff = ((w) & 0x1FF80u) | lane4;                     \
        const unsigned ab = *(const unsigned*)((const char*)AB2p + voff);   \
        float a2v;                                                          \
        asm("v_cvt_f32_f16 %0, %1" : "=v"(a2v) : "v"(ab));                  \
        dst += fast_exp2(fmaf(-qf, __int_as_float(ab & 0xFFFF0000u), a2v)); \
    }

__global__ __launch_bounds__(512) void fused_reduce_kernel(
    const unsigned* __restrict__ AB2p, const unsigned* __restrict__ payload,
    const int* __restrict__ gcur, float* __restrict__ out, int K)
{
    __shared__ unsigned sorted[SCAP];   // 12 KB
    __shared__ int h[64];
    __shared__ int pfx[64];
    const int t = threadIdx.x;
    const int bkt = blockIdx.x >> 1;    // 128-seq region
    const int sp  = blockIdx.x & 1;     // which 64-seq half
    const int s32 = t & 31;             // sample
    const int half = (t >> 5) & 1;      // gene-pair half
    const int wv = t >> 6;              // wave id 0..7
    const unsigned lane4 = (unsigned)(s32 << 2);
    const int start = bkt << CAPLG;
    const int n = min(gcur[bkt], CAP);

    if (t < 64) h[t] = 0;
    __syncthreads();

    // load full region (8/thread), keep only my half; rank-in-register
    unsigned r[8];
    int rk[8];
#pragma unroll
    for (int u = 0; u < 8; u++) {
        const int idx = t + u * 512;
        rk[u] = -1;
        if (idx < n) {
            const unsigned w = payload[start + idx];
            if ((int)((w >> 6) & 1u) == sp) {
                r[u] = w;
                rk[u] = atomicAdd(&h[w & 63], 1);
            }
        }
    }
    __syncthreads();

    // 64-bin exclusive scan by wave 0
    if (t < 64) {
        const int v = h[t];
        int incl = v;
#pragma unroll
        for (int d = 1; d < 64; d <<= 1) {
            const int x = __shfl_up(incl, d);
            if (t >= d) incl += x;
        }
        pfx[t] = incl - v;
    }
    __syncthreads();

    // scatter: plain ds_write (no atomics); guard vs SCAP overflow
#pragma unroll
    for (int u = 0; u < 8; u++)
        if (rk[u] >= 0) {
            const int d = pfx[r[u] & 63] + rk[u];
            if (d < SCAP) sorted[d] = r[u];
        }
    __syncthreads();

    // wave-paired accumulate: 4 genes per iter (2 per half), 2 exp chains
    const int seqbase = (bkt << 7) + (sp << 6) + (wv << 3);
    for (int q = 0; q < 8; q++) {
        const int ls = (wv << 3) + q;
        int i = pfx[ls];
        const int e = min(i + h[ls], SCAP);
        float a0 = 0.0f, a1 = 0.0f;
        for (; i + 3 < e; i += 4) {
            const int ix = i + (half << 1);
            const unsigned w0 = sorted[ix];
            const unsigned w1 = sorted[ix + 1];
            GENE(w0, a0); GENE(w1, a1);
        }
        for (; i + 1 < e; i += 2) {
            const unsigned w0 = sorted[i + half];
            GENE(w0, a0);
        }
        if (i < e && half == 0) {
            const unsigned w0 = sorted[i];
            GENE(w0, a0);
        }
        float acc = a0 + a1;
        acc += __shfl_xor(acc, 32);          // merge the two halves
        const int seq = seqbase + q;
        if (half == 0 && seq < K) out[(seq << 5) + s32] = acc;
    }
}

// ---- fallback (round-1 atomic version) ------------------------------------
__global__ __launch_bounds__(256) void scatter_exp_fallback(
    const float* __restrict__ A, const float* __restrict__ B,
    const float* __restrict__ pos, const int* __restrict__ gidx,
    const int* __restrict__ sidx, float* __restrict__ out, int M)
{
    const int lane = threadIdx.x & 31;
    int group = (int)((blockIdx.x * blockDim.x + threadIdx.x) >> 5);
    const int stride = (int)((gridDim.x * blockDim.x) >> 5);
    for (int g = group; g < M; g += stride) {
        const int gi = gidx[g];
        const int si = sidx[g];
        const float p = pos[g];
        const float a = A[(gi << 5) + lane];
        const float b = B[(gi << 5) + lane];
        atomicAdd(&out[(si << 5) + lane], __expf(fmaf(-p, b, a + 1.0f)));
    }
}

extern "C" void kernel_launch(void* const* d_in, const int* in_sizes, int n_in,
                              void* d_out, int out_size, void* d_ws, size_t ws_size,
                              hipStream_t stream)
{
    const float* A    = (const float*)d_in[0];   // [N,32]
    const float* B    = (const float*)d_in[1];   // [N,32]
    const float* pos  = (const float*)d_in[2];   // [M]
    const int*   gidx = (const int*)d_in[3];     // [M]
    const int*   sidx = (const int*)d_in[4];     // [M]
    float*       out  = (float*)d_out;           // [K,32]

    const int M  = in_sizes[2];
    const int NS = in_sizes[0];                  // N*32
    const int N  = NS / 32;
    const int K  = out_size / 32;
    const int NB = (K + 127) >> 7;               // 782 for K=100k
    const int NBLK = (M + CHUNK - 1) / CHUNK;    // 245 for M=2M

    // ws layout: gcur i32[NBMAX] | AB2p u32[N*32] | payload u32[NB<<CAPLG]
    char* ws = (char*)d_ws;
    size_t off = 0;
    int* gcur = (int*)(ws + off);       off += (size_t)NBMAX * sizeof(int);
    off = (off + 255) & ~(size_t)255;
    unsigned* AB2p = (unsigned*)(ws + off); off += (size_t)N * 32 * sizeof(unsigned);
    off = (off + 255) & ~(size_t)255;
    unsigned* payload = (unsigned*)(ws + off);
    const size_t need = off + ((size_t)NB << CAPLG) * sizeof(unsigned);

    // pack limits: local seq 7b, gidx 10b (N<=1024), pos_q 15b; mean bucket
    // fill must be well under CAP (guarded writes handle the tail)
    const bool packable = (NB <= NBMAX) && (K <= NBMAX * 128) && (N <= 1024)
                       && (M / (NB > 0 ? NB : 1) <= CAP / 4 * 3);
    if (!packable || ws_size < need) {
        hipMemsetAsync(d_out, 0, (size_t)out_size * sizeof(float), stream);
        scatter_exp_fallback<<<8192, 256, 0, stream>>>(A, B, pos, gidx, sidx, out, M);
        return;
    }

    const int prep_grid = (max(NS, NBMAX) + 255) / 256;
    prep_kernel     <<<prep_grid, 256, 0, stream>>>(A, B, AB2p, gcur, NS);
    partition_kernel<<<NBLK, 1024, 0, stream>>>(pos, gidx, sidx, gcur, payload, M, NB);
    fused_reduce_kernel<<<NB * 2, 512, 0, stream>>>(AB2p, payload, gcur, out, K);
}

// Round 13
// 57.272 us; speedup vs baseline: 1.3884x; 1.0494x over previous
//
#include <hip/hip_runtime.h>
#include <hip/hip_bf16.h>

// out[k,s] = sum_{g: seq[g]==k} exp(A[gi,s] + 1 - pos[g]*B[gi,s]),
// N=1000, S=32, M=2M, K=100k.
//
// Round 13. Two cuts vs r12:
//  - partition: rank-in-register (hist atomicAdd returns rank) -> single
//    global read of (sidx,gidx,pos), no cur-atomics, one fewer phase.
//  - reduce: 16-lane gene groups; lane owns a SAMPLE PAIR via dwordx2.
//    Per 4 genes: 1 ds_read + 1 global load + ~15 VALU (vs 2+4+~28).
//    Tail gated branchlessly (exp2(-2000)=0); unroll-2; shfl_xor(16,32)
//    merge; float2 stores from lanes 0-15.

#define CHUNK 8192        // genes per partition block
#define NBMAX 1024        // max 128-seq buckets (K <= 131072)
#define CAPLG 12          // per-bucket region = 4096 entries
#define CAP   (1 << CAPLG)
#define SCAP  3072        // sorted capacity per half-region (mean fill 1280)

__device__ inline float fast_exp2(float x) {
    float r;
    asm("v_exp_f32 %0, %1" : "=v"(r) : "v"(x));
    return r;
}

// ---- 0: pack AB2p[gi*32+s] = f16((A+1)*log2e) | bf16(B*log2e/2^15)<<16
//         and zero gcur[NBMAX]
__global__ __launch_bounds__(256) void prep_kernel(
    const float* __restrict__ A, const float* __restrict__ B,
    unsigned* __restrict__ AB2p, int* __restrict__ gcur, int NS)
{
    const int i = blockIdx.x * 256 + threadIdx.x;
    if (i < NBMAX) gcur[i] = 0;
    if (i >= NS) return;
    const float a2 = (A[i] + 1.0f) * 1.44269504f;
    const float b2 = B[i] * (1.44269504f / 32768.0f);
    const _Float16 ha = (_Float16)a2;                       // RNE cvt
    const unsigned short ua = __builtin_bit_cast(unsigned short, ha);
    unsigned bb = __float_as_uint(b2);
    bb = (bb + 0x7FFFu + ((bb >> 16) & 1u)) & 0xFFFF0000u;  // RNE to bf16
    AB2p[i] = (unsigned)ua | bb;
}

// ---- 1: partition, rank-in-register counting sort + atomic range claim ----
__global__ __launch_bounds__(1024) void partition_kernel(
    const float* __restrict__ pos, const int* __restrict__ gidx,
    const int* __restrict__ sidx, int* __restrict__ gcur,
    unsigned* __restrict__ payload, int M, int NB)
{
    __shared__ int h[NBMAX];
    __shared__ int pfx[NBMAX];
    __shared__ int dbase[NBMAX];
    __shared__ int wsum[16];
    __shared__ unsigned stg_p[CHUNK];        // 32 KB packed payload
    __shared__ unsigned short stg_b[CHUNK];  // 16 KB bucket of each slot
    const int t = threadIdx.x, blk = blockIdx.x;
    const int i0 = blk * CHUNK;
    const int n = min(CHUNK, M - i0);

    h[t] = 0;
    __syncthreads();

    // single pass: load tuples to registers, pack, hist+rank
    unsigned pl[8];
    int bb[8], rk[8];
#pragma unroll
    for (int u = 0; u < 8; u++) {
        const int j = t + u * 1024;
        rk[u] = -1;
        if (j < n) {
            const int sx = sidx[i0 + j];
            const int b = sx >> 7;
            const float p = pos[i0 + j];
            int q = (int)fmaf(p, 32768.0f, 0.5f);
            q = min(q, 32767);
            pl[u] = (unsigned)(sx & 127)
                  | ((unsigned)gidx[i0 + j] << 7)
                  | ((unsigned)q << 17);
            bb[u] = b;
            rk[u] = atomicAdd(&h[b], 1);
        }
    }
    __syncthreads();

    // block-wide exclusive scan over 1024 bins (wave shfl + wave sums)
    {
        const int v = h[t];
        int incl = v;
#pragma unroll
        for (int d = 1; d < 64; d <<= 1) {
            const int x = __shfl_up(incl, d);
            if ((t & 63) >= d) incl += x;
        }
        if ((t & 63) == 63) wsum[t >> 6] = incl;
        __syncthreads();
        if (t < 16) {
            const int wv = wsum[t];
            int winc = wv;
#pragma unroll
            for (int d = 1; d < 16; d <<= 1) {
                const int x = __shfl_up(winc, d, 16);
                if (t >= d) winc += x;
            }
            wsum[t] = winc - wv;
        }
        __syncthreads();
        pfx[t] = wsum[t >> 6] + incl - v;
    }
    __syncthreads();

    // staging scatter using register ranks (plain ds_write, no atomics)
#pragma unroll
    for (int u = 0; u < 8; u++)
        if (rk[u] >= 0) {
            const int d = pfx[bb[u]] + rk[u];
            stg_p[d] = pl[u];
            stg_b[d] = (unsigned short)bb[u];
        }
    __syncthreads();

    // claim this block's range in each bucket's fixed region
    if (t < NB) {
        const int hc = h[t];
        int dst = t << CAPLG;
        if (hc > 0) dst += atomicAdd(&gcur[t], hc);
        dbase[t] = dst;
    }
    __syncthreads();

    // coalesced flush; guard against (statistically impossible) overflow
    for (int tt = t; tt < n; tt += 1024) {
        const int b = stg_b[tt];
        const int r = dbase[b] + (tt - pfx[b]);
        if ((r >> CAPLG) == b) payload[r] = stg_p[tt];
    }
}

// ---- 2: fused half-region sort-by-seq + 16-lane-group register reduce -----
// Block = 512 threads = 8 waves; handles the 64-seq half (bit 6) of a
// 128-seq region. Wave w owns local seqs 8w..8w+7. Within a wave: 4 gene
// groups of 16 lanes; lane l16 covers samples 2*l16, 2*l16+1 via dwordx2.
__global__ __launch_bounds__(512) void fused_reduce_kernel(
    const unsigned* __restrict__ AB2p, const unsigned* __restrict__ payload,
    const int* __restrict__ gcur, float* __restrict__ out, int K)
{
    __shared__ unsigned sorted[SCAP + 8];   // +8: tail over-read slack
    __shared__ int h[64];
    __shared__ int pfx[64];
    const int t = threadIdx.x;
    const int bkt = blockIdx.x >> 1;    // 128-seq region
    const int sp  = blockIdx.x & 1;     // which 64-seq half
    const int g4  = (t >> 4) & 3;       // gene group within wave (0..3)
    const int l16 = t & 15;             // sample-pair id
    const unsigned lane8 = (unsigned)(l16 << 3);
    const int wv = t >> 6;              // wave id 0..7
    const int start = bkt << CAPLG;
    const int n = min(gcur[bkt], CAP);

    if (t < 64) h[t] = 0;
    __syncthreads();

    // load full region (8/thread), keep my half; rank-in-register
    unsigned r[8];
    int rk[8];
#pragma unroll
    for (int u = 0; u < 8; u++) {
        const int idx = t + u * 512;
        rk[u] = -1;
        if (idx < n) {
            const unsigned w = payload[start + idx];
            if ((int)((w >> 6) & 1u) == sp) {
                r[u] = w;
                rk[u] = atomicAdd(&h[w & 63], 1);
            }
        }
    }
    __syncthreads();

    // 64-bin exclusive scan by wave 0
    if (t < 64) {
        const int v = h[t];
        int incl = v;
#pragma unroll
        for (int d = 1; d < 64; d <<= 1) {
            const int x = __shfl_up(incl, d);
            if (t >= d) incl += x;
        }
        pfx[t] = incl - v;
    }
    __syncthreads();

    // scatter: plain ds_write; guard vs SCAP overflow
#pragma unroll
    for (int u = 0; u < 8; u++)
        if (rk[u] >= 0) {
            const int d = pfx[r[u] & 63] + rk[u];
            if (d < SCAP) sorted[d] = r[u];
        }
    __syncthreads();

    // accumulate: 4 genes per quad, 2 quads in flight (unroll-2)
#define GPROC(gi, A0, A1)                                                     \
    {                                                                         \
        const unsigned w = sorted[gi];                                        \
        const bool valid = (gi) < e;                                          \
        const unsigned voff = (w & 0x1FF80u) | lane8;                         \
        const uint2 ab = *(const uint2*)((const char*)AB2p + voff);           \
        const float qf = (float)(w >> 17);                                    \
        float fa0, fa1;                                                       \
        asm("v_cvt_f32_f16 %0, %1" : "=v"(fa0) : "v"(ab.x));                  \
        asm("v_cvt_f32_f16 %0, %1" : "=v"(fa1) : "v"(ab.y));                  \
        float x0 = fmaf(-qf, __int_as_float(ab.x & 0xFFFF0000u), fa0);        \
        float x1 = fmaf(-qf, __int_as_float(ab.y & 0xFFFF0000u), fa1);        \
        x0 = valid ? x0 : -2000.0f;                                           \
        x1 = valid ? x1 : -2000.0f;                                           \
        A0 += fast_exp2(x0);                                                  \
        A1 += fast_exp2(x1);                                                  \
    }

    const int seqbase = (bkt << 7) + (sp << 6) + (wv << 3);
    for (int q = 0; q < 8; q++) {
        const int ls = (wv << 3) + q;
        const int i0 = pfx[ls];
        const int e = min(i0 + h[ls], SCAP);
        float a0 = 0.0f, a1 = 0.0f, b0 = 0.0f, b1 = 0.0f;
        int i = i0;
        for (; i + 4 < e; i += 8) {
            GPROC(i + g4, a0, a1);
            GPROC(i + 4 + g4, b0, b1);
        }
        for (; i < e; i += 4)
            GPROC(i + g4, a0, a1);
        float acc0 = a0 + b0, acc1 = a1 + b1;
        acc0 += __shfl_xor(acc0, 16);
        acc1 += __shfl_xor(acc1, 16);
        acc0 += __shfl_xor(acc0, 32);
        acc1 += __shfl_xor(acc1, 32);
        const int seq = seqbase + q;
        if ((t & 48) == 0 && seq < K)
            *(float2*)&out[(seq << 5) + (l16 << 1)] = make_float2(acc0, acc1);
    }
#undef GPROC
}

// ---- fallback (round-1 atomic version) ------------------------------------
__global__ __launch_bounds__(256) void scatter_exp_fallback(
    const float* __restrict__ A, const float* __restrict__ B,
    const float* __restrict__ pos, const int* __restrict__ gidx,
    const int* __restrict__ sidx, float* __restrict__ out, int M)
{
    const int lane = threadIdx.x & 31;
    int group = (int)((blockIdx.x * blockDim.x + threadIdx.x) >> 5);
    const int stride = (int)((gridDim.x * blockDim.x) >> 5);
    for (int g = group; g < M; g += stride) {
        const int gi = gidx[g];
        const int si = sidx[g];
        const float p = pos[g];
        const float a = A[(gi << 5) + lane];
        const float b = B[(gi << 5) + lane];
        atomicAdd(&out[(si << 5) + lane], __expf(fmaf(-p, b, a + 1.0f)));
    }
}

extern "C" void kernel_launch(void* const* d_in, const int* in_sizes, int n_in,
                              void* d_out, int out_size, void* d_ws, size_t ws_size,
                              hipStream_t stream)
{
    const float* A    = (const float*)d_in[0];   // [N,32]
    const float* B    = (const float*)d_in[1];   // [N,32]
    const float* pos  = (const float*)d_in[2];   // [M]
    const int*   gidx = (const int*)d_in[3];     // [M]
    const int*   sidx = (const int*)d_in[4];     // [M]
    float*       out  = (float*)d_out;           // [K,32]

    const int M  = in_sizes[2];
    const int NS = in_sizes[0];                  // N*32
    const int N  = NS / 32;
    const int K  = out_size / 32;
    const int NB = (K + 127) >> 7;               // 782 for K=100k
    const int NBLK = (M + CHUNK - 1) / CHUNK;    // 245 for M=2M

    // ws layout: gcur i32[NBMAX] | AB2p u32[N*32] | payload u32[NB<<CAPLG]
    char* ws = (char*)d_ws;
    size_t off = 0;
    int* gcur = (int*)(ws + off);       off += (size_t)NBMAX * sizeof(int);
    off = (off + 255) & ~(size_t)255;
    unsigned* AB2p = (unsigned*)(ws + off); off += (size_t)N * 32 * sizeof(unsigned);
    off = (off + 255) & ~(size_t)255;
    unsigned* payload = (unsigned*)(ws + off);
    const size_t need = off + ((size_t)NB << CAPLG) * sizeof(unsigned);

    // pack limits: local seq 7b, gidx 10b (N<=1024), pos_q 15b; mean bucket
    // fill must be well under CAP (guarded writes handle the tail)
    const bool packable = (NB <= NBMAX) && (K <= NBMAX * 128) && (N <= 1024)
                       && (M / (NB > 0 ? NB : 1) <= CAP / 4 * 3);
    if (!packable || ws_size < need) {
        hipMemsetAsync(d_out, 0, (size_t)out_size * sizeof(float), stream);
        scatter_exp_fallback<<<8192, 256, 0, stream>>>(A, B, pos, gidx, sidx, out, M);
        return;
    }

    const int prep_grid = (max(NS, NBMAX) + 255) / 256;
    prep_kernel     <<<prep_grid, 256, 0, stream>>>(A, B, AB2p, gcur, NS);
    partition_kernel<<<NBLK, 1024, 0, stream>>>(pos, gidx, sidx, gcur, payload, M, NB);
    fused_reduce_kernel<<<NB * 2, 512, 0, stream>>>(AB2p, payload, gcur, out, K);
}